// Round 7
// baseline (223.841 us; speedup 1.0000x reference)
//
#include <hip/hip_runtime.h>
#include <stdint.h>

#define MARGIN 0.3f
#define EPS 1e-12f

typedef __attribute__((ext_vector_type(8))) __bf16 bf16x8;
typedef __attribute__((ext_vector_type(4))) float f32x4;

// round-to-nearest-even fp32 -> bf16
__device__ __forceinline__ unsigned short f2bf(float f) {
    unsigned u = __float_as_uint(f);
    unsigned r = (u + 0x7FFFu + ((u >> 16) & 1u)) >> 16;
    return (unsigned short)r;
}

// ---------------------------------------------------------------------------
// Kernel 1: fp32 -> bf16 convert, fp32 row norms, init ap/an/ctr.
// One WAVE per row (no __syncthreads, no LDS). grid = n/4 blocks of 256.
// ---------------------------------------------------------------------------
__global__ __launch_bounds__(256) void prep_kernel(
    const float* __restrict__ X, unsigned short* __restrict__ Xbf,
    float* __restrict__ sqg, unsigned* __restrict__ apb,
    unsigned* __restrict__ anb, unsigned* __restrict__ ctr, int d) {
    const int wave = threadIdx.x >> 6, lane = threadIdx.x & 63;
    const int row = blockIdx.x * 4 + wave;
    const float4* Xr = (const float4*)(X + (size_t)row * d);
    ushort4* Or = (ushort4*)(Xbf + (size_t)row * d);
    float s = 0.0f;
    const int nq = d >> 2;
    for (int i = lane; i < nq; i += 64) {
        float4 v = Xr[i];
        s += v.x * v.x + v.y * v.y + v.z * v.z + v.w * v.w;
        ushort4 o;
        o.x = f2bf(v.x); o.y = f2bf(v.y); o.z = f2bf(v.z); o.w = f2bf(v.w);
        Or[i] = o;
    }
    for (int off = 32; off > 0; off >>= 1) s += __shfl_down(s, off, 64);
    if (lane == 0) {
        sqg[row] = s;
        apb[row] = 0u;            // dist >= 0: uint compare == float compare
        anb[row] = 0x7F800000u;   // +inf
    }
    if (blockIdx.x == 0 && threadIdx.x == 0) ctr[0] = 0u;
}

// ---------------------------------------------------------------------------
// Kernel 2: triangular fused Gram + distance + dual-side hard mining.
// NO LDS, NO BARRIERS in the main loop: each wave loads its MFMA fragments
// directly global->register (matrix is L2/L3-resident), two named register
// sets, K unrolled x2 -> compiler emits counted vmcnt, waves run free.
// Fragment addresses identical to the (verified) LDS-path layout.
// Last block (atomic counter) computes the final loss/precision.
// ---------------------------------------------------------------------------
#define BM 128
#define BN 128
#define BK 32

__global__ __launch_bounds__(256) void tri_gemm(
    const unsigned short* __restrict__ Xbf, const float* __restrict__ sqg,
    const int* __restrict__ tgt, unsigned* __restrict__ apb,
    unsigned* __restrict__ anb, unsigned* __restrict__ ctr,
    float* __restrict__ out, int n, int d, int nblk) {
    const int tid  = threadIdx.x;
    const int lane = tid & 63;
    const int wave = tid >> 6;
    const int wm = wave >> 1, wn = wave & 1;
    const int lo = lane & 15, hi = lane >> 4;

    // bijective XCD swizzle (m204): consecutive triangular bids (which share
    // the A row-band) stay on one XCD's L2.
    const int orig = blockIdx.x;
    const int q = nblk >> 3, r = nblk & 7;
    const int xcd = orig & 7, idx = orig >> 3;
    const int bid = (xcd < r ? xcd * (q + 1) : r * (q + 1) + (xcd - r) * q) + idx;

    // triangular block index: bid -> (bi, bj), bi >= bj
    int bi = (int)((sqrtf(8.0f * (float)bid + 1.0f) - 1.0f) * 0.5f);
    while ((bi + 1) * (bi + 2) / 2 <= bid) ++bi;
    while (bi * (bi + 1) / 2 > bid) --bi;
    const int bj = bid - bi * (bi + 1) / 2;
    const int rowBase = bi * BM;
    const int colBase = bj * BN;
    const bool offdiag = (bi != bj);

    // per-thread fragment base pointers (k=0), same layout as verified LDS path
    const unsigned short* pA[4];
    const unsigned short* pB[4];
#pragma unroll
    for (int mi = 0; mi < 4; ++mi)
        pA[mi] = Xbf + (size_t)(rowBase + wm * 64 + mi * 16 + lo) * d + hi * 8;
#pragma unroll
    for (int ni = 0; ni < 4; ++ni)
        pB[ni] = Xbf + (size_t)(colBase + wn * 64 + ni * 16 + lo) * d + hi * 8;

    f32x4 acc[4][4] = {};
    bf16x8 a0[4], b0[4], a1[4], b1[4];

    // prologue: set0 <- k=0
#pragma unroll
    for (int i = 0; i < 4; ++i) {
        a0[i] = *(const bf16x8*)(pA[i]);
        b0[i] = *(const bf16x8*)(pB[i]);
    }

    for (int k0 = 0; k0 < d; k0 += 2 * BK) {
        const int k1 = k0 + BK;                       // always < d (d % 64 == 0)
        const int k2 = (k1 + BK < d) ? k1 + BK : 0;   // wrap on last iter (discarded)
        // load set1 <- k1 (MFMAs below cover the latency)
#pragma unroll
        for (int i = 0; i < 4; ++i) {
            a1[i] = *(const bf16x8*)(pA[i] + k1);
            b1[i] = *(const bf16x8*)(pB[i] + k1);
        }
        // MFMA on set0 (k0)
#pragma unroll
        for (int mi = 0; mi < 4; ++mi)
#pragma unroll
            for (int ni = 0; ni < 4; ++ni)
                acc[mi][ni] = __builtin_amdgcn_mfma_f32_16x16x32_bf16(
                    a0[mi], b0[ni], acc[mi][ni], 0, 0, 0);
        // load set0 <- k2
#pragma unroll
        for (int i = 0; i < 4; ++i) {
            a0[i] = *(const bf16x8*)(pA[i] + k2);
            b0[i] = *(const bf16x8*)(pB[i] + k2);
        }
        // MFMA on set1 (k1)
#pragma unroll
        for (int mi = 0; mi < 4; ++mi)
#pragma unroll
            for (int ni = 0; ni < 4; ++ni)
                acc[mi][ni] = __builtin_amdgcn_mfma_f32_16x16x32_bf16(
                    a1[mi], b1[ni], acc[mi][ni], 0, 0, 0);
    }

    // ---------------- epilogue (unchanged, verified) ----------------
    float sqj[4];
    int   tj[4];
#pragma unroll
    for (int ni = 0; ni < 4; ++ni) {
        const int gj = colBase + wn * 64 + ni * 16 + lo;
        sqj[ni] = sqg[gj];
        tj[ni]  = tgt[gj];
    }
    float cap[4], can[4];
#pragma unroll
    for (int ni = 0; ni < 4; ++ni) { cap[ni] = 0.0f; can[ni] = __uint_as_float(0x7F800000u); }

#pragma unroll
    for (int mi = 0; mi < 4; ++mi) {
#pragma unroll
        for (int j = 0; j < 4; ++j) {
            const int gi = rowBase + wm * 64 + mi * 16 + hi * 4 + j;
            const float sqi = sqg[gi];
            const int   ti  = tgt[gi];
            float ap = 0.0f;
            float an = __uint_as_float(0x7F800000u);
#pragma unroll
            for (int ni = 0; ni < 4; ++ni) {
                const float d2 = sqi + sqj[ni] - 2.0f * acc[mi][ni][j];
                const float dist = sqrtf(fmaxf(d2, EPS));
                if (ti == tj[ni]) {
                    ap = fmaxf(ap, dist);
                    cap[ni] = fmaxf(cap[ni], dist);
                } else {
                    an = fminf(an, dist);
                    can[ni] = fminf(can[ni], dist);
                }
            }
#pragma unroll
            for (int m = 1; m < 16; m <<= 1) {
                ap = fmaxf(ap, __shfl_xor(ap, m, 64));
                an = fminf(an, __shfl_xor(an, m, 64));
            }
            if (lo == 0) {
                atomicMax(&apb[gi], __float_as_uint(ap));
                atomicMin(&anb[gi], __float_as_uint(an));
            }
        }
    }
    if (offdiag) {
#pragma unroll
        for (int ni = 0; ni < 4; ++ni) {
            float ap = cap[ni], an = can[ni];
#pragma unroll
            for (int m = 16; m < 64; m <<= 1) {
                ap = fmaxf(ap, __shfl_xor(ap, m, 64));
                an = fminf(an, __shfl_xor(an, m, 64));
            }
            if (hi == 0) {
                const int gj = colBase + wn * 64 + ni * 16 + lo;
                atomicMax(&apb[gj], __float_as_uint(ap));
                atomicMin(&anb[gj], __float_as_uint(an));
            }
        }
    }

    // ---------------- last-block finalize ----------------
    __threadfence();
    __syncthreads();
    __shared__ int lastFlag;
    if (tid == 0) {
        unsigned prev = __hip_atomic_fetch_add(ctr, 1u, __ATOMIC_ACQ_REL,
                                               __HIP_MEMORY_SCOPE_AGENT);
        lastFlag = (prev == (unsigned)(nblk - 1)) ? 1 : 0;
    }
    __syncthreads();
    if (lastFlag) {
        float ls = 0.0f, pc = 0.0f;
        for (int i = tid; i < n; i += 256) {
            const float ap = __uint_as_float(__hip_atomic_load(
                &apb[i], __ATOMIC_RELAXED, __HIP_MEMORY_SCOPE_AGENT));
            const float an = __uint_as_float(__hip_atomic_load(
                &anb[i], __ATOMIC_RELAXED, __HIP_MEMORY_SCOPE_AGENT));
            ls += fmaxf(MARGIN - (an - ap), 0.0f);
            pc += (an > ap) ? 1.0f : 0.0f;
        }
        __shared__ float rl[4], rp[4];
        for (int off = 32; off > 0; off >>= 1) {
            ls += __shfl_down(ls, off, 64);
            pc += __shfl_down(pc, off, 64);
        }
        if ((tid & 63) == 0) { rl[tid >> 6] = ls; rp[tid >> 6] = pc; }
        __syncthreads();
        if (tid == 0) {
            out[0] = (rl[0] + rl[1] + rl[2] + rl[3]) / (float)n;
            out[1] = (rp[0] + rp[1] + rp[2] + rp[3]) / (float)n;
        }
    }
}

// ---------------------------------------------------------------------------
// Fallback path (only if ws_size too small): pure fp32, zero workspace.
// ---------------------------------------------------------------------------
__global__ __launch_bounds__(256) void fb_zero(float* __restrict__ out) {
    if (threadIdx.x == 0) { out[0] = 0.0f; out[1] = 0.0f; }
}

__global__ __launch_bounds__(256) void fb_row(
    const float* __restrict__ X, const int* __restrict__ tgt,
    float* __restrict__ out, int n, int d) {
    __shared__ float xi[4096];  // supports d <= 4096
    const int i = blockIdx.x;
    const int tid = threadIdx.x;
    for (int k = tid; k < d; k += 256) xi[k] = X[(size_t)i * d + k];
    __syncthreads();
    const int ti = tgt[i];
    float ap = 0.0f;
    float an = __uint_as_float(0x7F800000u);
    for (int j = tid; j < n; j += 256) {
        const float4* Xj = (const float4*)(X + (size_t)j * d);
        float s = 0.0f;
        for (int k4 = 0; k4 < (d >> 2); ++k4) {
            float4 v = Xj[k4];
            float4 u = *(const float4*)&xi[k4 * 4];
            float dx = u.x - v.x, dy = u.y - v.y, dz = u.z - v.z, dw = u.w - v.w;
            s += dx * dx + dy * dy + dz * dz + dw * dw;
        }
        const float dist = sqrtf(fmaxf(s, EPS));
        if (tgt[j] == ti) ap = fmaxf(ap, dist);
        else              an = fminf(an, dist);
    }
    for (int m = 1; m < 64; m <<= 1) {
        ap = fmaxf(ap, __shfl_xor(ap, m, 64));
        an = fminf(an, __shfl_xor(an, m, 64));
    }
    __shared__ float rap[4], ran[4];
    const int wave = tid >> 6, lane = tid & 63;
    if (lane == 0) { rap[wave] = ap; ran[wave] = an; }
    __syncthreads();
    if (tid == 0) {
        ap = fmaxf(fmaxf(rap[0], rap[1]), fmaxf(rap[2], rap[3]));
        an = fminf(fminf(ran[0], ran[1]), fminf(ran[2], ran[3]));
        atomicAdd(&out[0], fmaxf(MARGIN - (an - ap), 0.0f));
        atomicAdd(&out[1], (an > ap) ? 1.0f : 0.0f);
    }
}

__global__ __launch_bounds__(64) void fb_scale(float* __restrict__ out, float inv_n) {
    if (threadIdx.x == 0) { out[0] *= inv_n; out[1] *= inv_n; }
}

// ---------------------------------------------------------------------------
extern "C" void kernel_launch(void* const* d_in, const int* in_sizes, int n_in,
                              void* d_out, int out_size, void* d_ws, size_t ws_size,
                              hipStream_t stream) {
    const float* X   = (const float*)d_in[0];
    const int*   tgt = (const int*)d_in[1];
    const int n = in_sizes[1];
    const int d = in_sizes[0] / n;

    const size_t need = (size_t)n * d * 2 + (size_t)n * 4 * 3 + 4;
    if (ws_size >= need) {
        char* ws = (char*)d_ws;
        unsigned short* Xbf = (unsigned short*)ws;                 // n*d*2 B
        float*    sqg = (float*)(ws + (size_t)n * d * 2);          // n*4 B
        unsigned* apb = (unsigned*)((char*)sqg + (size_t)n * 4);   // n*4 B
        unsigned* anb = apb + n;                                   // n*4 B
        unsigned* ctr = anb + n;                                   // 4 B

        const int nb = n / BM;
        const int nblk = nb * (nb + 1) / 2;
        prep_kernel<<<n / 4, 256, 0, stream>>>(X, Xbf, sqg, apb, anb, ctr, d);
        tri_gemm<<<nblk, 256, 0, stream>>>(Xbf, sqg, tgt, apb, anb, ctr,
                                           (float*)d_out, n, d, nblk);
    } else {
        fb_zero<<<1, 256, 0, stream>>>((float*)d_out);
        fb_row<<<n, 256, 0, stream>>>(X, tgt, (float*)d_out, n, d);
        fb_scale<<<1, 64, 0, stream>>>((float*)d_out, 1.0f / (float)n);
    }
}

// Round 8
// 176.155 us; speedup vs baseline: 1.2707x; 1.2707x over previous
//
#include <hip/hip_runtime.h>
#include <stdint.h>

#define MARGIN 0.3f
#define EPS 1e-12f

typedef __attribute__((ext_vector_type(8))) __bf16 bf16x8;
typedef __attribute__((ext_vector_type(4))) float f32x4;

// round-to-nearest-even fp32 -> bf16
__device__ __forceinline__ unsigned short f2bf(float f) {
    unsigned u = __float_as_uint(f);
    unsigned r = (u + 0x7FFFu + ((u >> 16) & 1u)) >> 16;
    return (unsigned short)r;
}

#define GLD16(gp, lp)                                                     \
    __builtin_amdgcn_global_load_lds(                                     \
        (const __attribute__((address_space(1))) void*)(gp),              \
        (__attribute__((address_space(3))) void*)(lp), 16, 0, 0)

// ---------------------------------------------------------------------------
// Kernel 1: fp32 -> bf16 convert, fp32 row norms, init ap/an/ctr.
// One WAVE per row (no __syncthreads, no LDS). grid = n/4 blocks of 256.
// ---------------------------------------------------------------------------
__global__ __launch_bounds__(256) void prep_kernel(
    const float* __restrict__ X, unsigned short* __restrict__ Xbf,
    float* __restrict__ sqg, unsigned* __restrict__ apb,
    unsigned* __restrict__ anb, unsigned* __restrict__ ctr, int d) {
    const int wave = threadIdx.x >> 6, lane = threadIdx.x & 63;
    const int row = blockIdx.x * 4 + wave;
    const float4* Xr = (const float4*)(X + (size_t)row * d);
    ushort4* Or = (ushort4*)(Xbf + (size_t)row * d);
    float s = 0.0f;
    const int nq = d >> 2;
    for (int i = lane; i < nq; i += 64) {
        float4 v = Xr[i];
        s += v.x * v.x + v.y * v.y + v.z * v.z + v.w * v.w;
        ushort4 o;
        o.x = f2bf(v.x); o.y = f2bf(v.y); o.z = f2bf(v.z); o.w = f2bf(v.w);
        Or[i] = o;
    }
    for (int off = 32; off > 0; off >>= 1) s += __shfl_down(s, off, 64);
    if (lane == 0) {
        sqg[row] = s;
        apb[row] = 0u;            // dist >= 0: uint compare == float compare
        anb[row] = 0x7F800000u;   // +inf
    }
    if (blockIdx.x == 0 && threadIdx.x == 0) ctr[0] = 0u;
}

// ---------------------------------------------------------------------------
// Kernel 2: triangular fused Gram + distance + dual-side hard mining.
// 512 threads = 8 waves (2 row-groups x 4 col-groups); each wave owns a
// 64x32 output sub-tile (4x2 frags of 16x16x32 bf16). Coalesced
// global_load_lds staging, 2-phase double-buffered (stage t+1, compute t,
// vmcnt(0)+barrier once per step). 16 waves/CU resident (2 blocks/CU).
// Last block (atomic counter) computes the final loss/precision.
// ---------------------------------------------------------------------------
#define BM 128
#define BN 128
#define BK 32

__global__ __launch_bounds__(512, 4) void tri_gemm(
    const unsigned short* __restrict__ Xbf, const float* __restrict__ sqg,
    const int* __restrict__ tgt, unsigned* __restrict__ apb,
    unsigned* __restrict__ anb, unsigned* __restrict__ ctr,
    float* __restrict__ out, int n, int d, int nblk) {
    __shared__ unsigned short ldsA[2][BM * BK];
    __shared__ unsigned short ldsB[2][BN * BK];

    const int tid  = threadIdx.x;
    const int lane = tid & 63;
    const int wave = tid >> 6;          // 0..7
    const int wm = wave >> 2;           // 0..1 (row group of 64)
    const int wn = wave & 3;            // 0..3 (col group of 32)
    const int lo = lane & 15, hi = lane >> 4;

    // bijective XCD swizzle (m204): consecutive triangular bids (which share
    // the A row-band) stay on one XCD's L2.
    const int orig = blockIdx.x;
    const int q = nblk >> 3, r = nblk & 7;
    const int xcd = orig & 7, idx = orig >> 3;
    const int bid = (xcd < r ? xcd * (q + 1) : r * (q + 1) + (xcd - r) * q) + idx;

    // triangular block index: bid -> (bi, bj), bi >= bj
    int bi = (int)((sqrtf(8.0f * (float)bid + 1.0f) - 1.0f) * 0.5f);
    while ((bi + 1) * (bi + 2) / 2 <= bid) ++bi;
    while (bi * (bi + 1) / 2 > bid) --bi;
    const int bj = bid - bi * (bi + 1) / 2;
    const int rowBase = bi * BM;
    const int colBase = bj * BN;
    const bool offdiag = (bi != bj);

    // staging: 8 A-chunks + 8 B-chunks of 1KB (16 rows x 32k); wave w takes
    // A-chunk w and B-chunk w.  lane -> (row lane>>2, k-off (lane&3)*8)
    const int lrow = lane >> 2;
    const int lk   = (lane & 3) * 8;
    const unsigned short* gA0 = Xbf + (size_t)(rowBase + wave * 16 + lrow) * d + lk;
    const unsigned short* gB0 = Xbf + (size_t)(colBase + wave * 16 + lrow) * d + lk;

    f32x4 acc[4][2] = {};

    const int nt = d / BK;
    int cur = 0;
    // prologue: stage tile 0
    GLD16(gA0, &ldsA[0][wave * 512]);
    GLD16(gB0, &ldsB[0][wave * 512]);
    asm volatile("s_waitcnt vmcnt(0)" ::: "memory");
    __syncthreads();

    for (int t = 0; t < nt; ++t) {
        if (t + 1 < nt) {
            const int k0 = (t + 1) * BK;
            GLD16(gA0 + k0, &ldsA[cur ^ 1][wave * 512]);
            GLD16(gB0 + k0, &ldsB[cur ^ 1][wave * 512]);
        }
        bf16x8 a[4], b[2];
#pragma unroll
        for (int mi = 0; mi < 4; ++mi)
            a[mi] = *(const bf16x8*)&ldsA[cur][(wm * 64 + mi * 16 + lo) * BK + hi * 8];
#pragma unroll
        for (int ni = 0; ni < 2; ++ni)
            b[ni] = *(const bf16x8*)&ldsB[cur][(wn * 32 + ni * 16 + lo) * BK + hi * 8];
#pragma unroll
        for (int mi = 0; mi < 4; ++mi)
#pragma unroll
            for (int ni = 0; ni < 2; ++ni)
                acc[mi][ni] = __builtin_amdgcn_mfma_f32_16x16x32_bf16(
                    a[mi], b[ni], acc[mi][ni], 0, 0, 0);
        if (t + 1 < nt) {
            asm volatile("s_waitcnt vmcnt(0)" ::: "memory");
            __syncthreads();
            cur ^= 1;
        }
    }

    // ---------------- epilogue (dual-side hard mining) ----------------
    float sqj[2];
    int   tj[2];
#pragma unroll
    for (int ni = 0; ni < 2; ++ni) {
        const int gj = colBase + wn * 32 + ni * 16 + lo;
        sqj[ni] = sqg[gj];
        tj[ni]  = tgt[gj];
    }
    float cap[2], can[2];
#pragma unroll
    for (int ni = 0; ni < 2; ++ni) { cap[ni] = 0.0f; can[ni] = __uint_as_float(0x7F800000u); }

#pragma unroll
    for (int mi = 0; mi < 4; ++mi) {
#pragma unroll
        for (int j = 0; j < 4; ++j) {
            const int gi = rowBase + wm * 64 + mi * 16 + hi * 4 + j;
            const float sqi = sqg[gi];
            const int   ti  = tgt[gi];
            float ap = 0.0f;
            float an = __uint_as_float(0x7F800000u);
#pragma unroll
            for (int ni = 0; ni < 2; ++ni) {
                const float d2 = sqi + sqj[ni] - 2.0f * acc[mi][ni][j];
                const float dist = sqrtf(fmaxf(d2, EPS));
                if (ti == tj[ni]) {
                    ap = fmaxf(ap, dist);
                    cap[ni] = fmaxf(cap[ni], dist);
                } else {
                    an = fminf(an, dist);
                    can[ni] = fminf(can[ni], dist);
                }
            }
            // row-side: reduce across the 16 lanes (lo) holding this row
#pragma unroll
            for (int m = 1; m < 16; m <<= 1) {
                ap = fmaxf(ap, __shfl_xor(ap, m, 64));
                an = fminf(an, __shfl_xor(an, m, 64));
            }
            if (lo == 0) {
                atomicMax(&apb[gi], __float_as_uint(ap));
                atomicMin(&anb[gi], __float_as_uint(an));
            }
        }
    }
    if (offdiag) {
        // col-side: reduce across the 4 hi groups (lane bits 4,5)
#pragma unroll
        for (int ni = 0; ni < 2; ++ni) {
            float ap = cap[ni], an = can[ni];
#pragma unroll
            for (int m = 16; m < 64; m <<= 1) {
                ap = fmaxf(ap, __shfl_xor(ap, m, 64));
                an = fminf(an, __shfl_xor(an, m, 64));
            }
            if (hi == 0) {
                const int gj = colBase + wn * 32 + ni * 16 + lo;
                atomicMax(&apb[gj], __float_as_uint(ap));
                atomicMin(&anb[gj], __float_as_uint(an));
            }
        }
    }

    // ---------------- last-block finalize ----------------
    __threadfence();
    __syncthreads();
    __shared__ int lastFlag;
    if (tid == 0) {
        unsigned prev = __hip_atomic_fetch_add(ctr, 1u, __ATOMIC_ACQ_REL,
                                               __HIP_MEMORY_SCOPE_AGENT);
        lastFlag = (prev == (unsigned)(nblk - 1)) ? 1 : 0;
    }
    __syncthreads();
    if (lastFlag) {
        float ls = 0.0f, pc = 0.0f;
        for (int i = tid; i < n; i += 512) {
            const float ap = __uint_as_float(__hip_atomic_load(
                &apb[i], __ATOMIC_RELAXED, __HIP_MEMORY_SCOPE_AGENT));
            const float an = __uint_as_float(__hip_atomic_load(
                &anb[i], __ATOMIC_RELAXED, __HIP_MEMORY_SCOPE_AGENT));
            ls += fmaxf(MARGIN - (an - ap), 0.0f);
            pc += (an > ap) ? 1.0f : 0.0f;
        }
        __shared__ float rl[8], rp[8];
        for (int off = 32; off > 0; off >>= 1) {
            ls += __shfl_down(ls, off, 64);
            pc += __shfl_down(pc, off, 64);
        }
        if ((tid & 63) == 0) { rl[tid >> 6] = ls; rp[tid >> 6] = pc; }
        __syncthreads();
        if (tid == 0) {
            float L = 0.0f, P = 0.0f;
#pragma unroll
            for (int w = 0; w < 8; ++w) { L += rl[w]; P += rp[w]; }
            out[0] = L / (float)n;
            out[1] = P / (float)n;
        }
    }
}

// ---------------------------------------------------------------------------
// Fallback path (only if ws_size too small): pure fp32, zero workspace.
// ---------------------------------------------------------------------------
__global__ __launch_bounds__(256) void fb_zero(float* __restrict__ out) {
    if (threadIdx.x == 0) { out[0] = 0.0f; out[1] = 0.0f; }
}

__global__ __launch_bounds__(256) void fb_row(
    const float* __restrict__ X, const int* __restrict__ tgt,
    float* __restrict__ out, int n, int d) {
    __shared__ float xi[4096];  // supports d <= 4096
    const int i = blockIdx.x;
    const int tid = threadIdx.x;
    for (int k = tid; k < d; k += 256) xi[k] = X[(size_t)i * d + k];
    __syncthreads();
    const int ti = tgt[i];
    float ap = 0.0f;
    float an = __uint_as_float(0x7F800000u);
    for (int j = tid; j < n; j += 256) {
        const float4* Xj = (const float4*)(X + (size_t)j * d);
        float s = 0.0f;
        for (int k4 = 0; k4 < (d >> 2); ++k4) {
            float4 v = Xj[k4];
            float4 u = *(const float4*)&xi[k4 * 4];
            float dx = u.x - v.x, dy = u.y - v.y, dz = u.z - v.z, dw = u.w - v.w;
            s += dx * dx + dy * dy + dz * dz + dw * dw;
        }
        const float dist = sqrtf(fmaxf(s, EPS));
        if (tgt[j] == ti) ap = fmaxf(ap, dist);
        else              an = fminf(an, dist);
    }
    for (int m = 1; m < 64; m <<= 1) {
        ap = fmaxf(ap, __shfl_xor(ap, m, 64));
        an = fminf(an, __shfl_xor(an, m, 64));
    }
    __shared__ float rap[4], ran[4];
    const int wave = tid >> 6, lane = tid & 63;
    if (lane == 0) { rap[wave] = ap; ran[wave] = an; }
    __syncthreads();
    if (tid == 0) {
        ap = fmaxf(fmaxf(rap[0], rap[1]), fmaxf(rap[2], rap[3]));
        an = fminf(fminf(ran[0], ran[1]), fminf(ran[2], ran[3]));
        atomicAdd(&out[0], fmaxf(MARGIN - (an - ap), 0.0f));
        atomicAdd(&out[1], (an > ap) ? 1.0f : 0.0f);
    }
}

__global__ __launch_bounds__(64) void fb_scale(float* __restrict__ out, float inv_n) {
    if (threadIdx.x == 0) { out[0] *= inv_n; out[1] *= inv_n; }
}

// ---------------------------------------------------------------------------
extern "C" void kernel_launch(void* const* d_in, const int* in_sizes, int n_in,
                              void* d_out, int out_size, void* d_ws, size_t ws_size,
                              hipStream_t stream) {
    const float* X   = (const float*)d_in[0];
    const int*   tgt = (const int*)d_in[1];
    const int n = in_sizes[1];
    const int d = in_sizes[0] / n;

    const size_t need = (size_t)n * d * 2 + (size_t)n * 4 * 3 + 4;
    if (ws_size >= need) {
        char* ws = (char*)d_ws;
        unsigned short* Xbf = (unsigned short*)ws;                 // n*d*2 B
        float*    sqg = (float*)(ws + (size_t)n * d * 2);          // n*4 B
        unsigned* apb = (unsigned*)((char*)sqg + (size_t)n * 4);   // n*4 B
        unsigned* anb = apb + n;                                   // n*4 B
        unsigned* ctr = anb + n;                                   // 4 B

        const int nb = n / BM;
        const int nblk = nb * (nb + 1) / 2;
        prep_kernel<<<n / 4, 256, 0, stream>>>(X, Xbf, sqg, apb, anb, ctr, d);
        tri_gemm<<<nblk, 512, 0, stream>>>(Xbf, sqg, tgt, apb, anb, ctr,
                                           (float*)d_out, n, d, nblk);
    } else {
        fb_zero<<<1, 256, 0, stream>>>((float*)d_out);
        fb_row<<<n, 256, 0, stream>>>(X, tgt, (float*)d_out, n, d);
        fb_scale<<<1, 64, 0, stream>>>((float*)d_out, 1.0f / (float)n);
    }
}

// Round 9
// 142.714 us; speedup vs baseline: 1.5685x; 1.2343x over previous
//
#include <hip/hip_runtime.h>
#include <stdint.h>

#define MARGIN 0.3f
#define EPS 1e-12f

typedef __attribute__((ext_vector_type(8))) __bf16 bf16x8;
typedef __attribute__((ext_vector_type(4))) float f32x4;

// round-to-nearest-even fp32 -> bf16
__device__ __forceinline__ unsigned short f2bf(float f) {
    unsigned u = __float_as_uint(f);
    unsigned r = (u + 0x7FFFu + ((u >> 16) & 1u)) >> 16;
    return (unsigned short)r;
}

#define GLD16(gp, lp)                                                     \
    __builtin_amdgcn_global_load_lds(                                     \
        (const __attribute__((address_space(1))) void*)(gp),              \
        (__attribute__((address_space(3))) void*)(lp), 16, 0, 0)

// ---------------------------------------------------------------------------
// Kernel 1: fp32 -> bf16 convert, fp32 row norms, init ap/an/ctr.
// One WAVE per row. grid = n/4 blocks of 256.
// ---------------------------------------------------------------------------
__global__ __launch_bounds__(256) void prep_kernel(
    const float* __restrict__ X, unsigned short* __restrict__ Xbf,
    float* __restrict__ sqg, unsigned* __restrict__ apb,
    unsigned* __restrict__ anb, unsigned* __restrict__ ctr, int d) {
    const int wave = threadIdx.x >> 6, lane = threadIdx.x & 63;
    const int row = blockIdx.x * 4 + wave;
    const float4* Xr = (const float4*)(X + (size_t)row * d);
    ushort4* Or = (ushort4*)(Xbf + (size_t)row * d);
    float s = 0.0f;
    const int nq = d >> 2;
    for (int i = lane; i < nq; i += 64) {
        float4 v = Xr[i];
        s += v.x * v.x + v.y * v.y + v.z * v.z + v.w * v.w;
        ushort4 o;
        o.x = f2bf(v.x); o.y = f2bf(v.y); o.z = f2bf(v.z); o.w = f2bf(v.w);
        Or[i] = o;
    }
    for (int off = 32; off > 0; off >>= 1) s += __shfl_down(s, off, 64);
    if (lane == 0) {
        sqg[row] = s;
        apb[row] = 0u;            // dist >= 0: uint compare == float compare
        anb[row] = 0x7F800000u;   // +inf
    }
    if (blockIdx.x == 0 && threadIdx.x == 0) ctr[0] = 0u;
}

// ---------------------------------------------------------------------------
// Kernel 2: 256x128-tile triangular-COVER Gram + distance + dual hard mining.
// Cover: tiles (I,J), I in [0,16) row-blocks of 256, J in [0, 2I+2) col-blocks
// of 128. Every unordered pair {i,j} appears in >=1 tile; min/max updates are
// idempotent so straddling-tile double-coverage is harmless.
// 8 waves (4M x 2N), per-wave 64x64 (4x4 frags of 16x16x32 bf16).
// Pipelined staging: double-buffered GLD16, counted vmcnt(3), raw s_barrier
// (NEVER __syncthreads in the loop -- it drains vmcnt, which is the stall).
// Last block (atomic counter) computes the final loss/precision.
// ---------------------------------------------------------------------------
#define BM 256
#define BN 128
#define BK 32

__global__ __launch_bounds__(512, 4) void tri_gemm(
    const unsigned short* __restrict__ Xbf, const float* __restrict__ sqg,
    const int* __restrict__ tgt, unsigned* __restrict__ apb,
    unsigned* __restrict__ anb, unsigned* __restrict__ ctr,
    float* __restrict__ out, int n, int d, int nblk) {
    __shared__ unsigned short ldsA[2][BM * BK];   // 2 x 16 KB
    __shared__ unsigned short ldsB[2][BN * BK];   // 2 x 8 KB

    const int tid  = threadIdx.x;
    const int lane = tid & 63;
    const int wave = tid >> 6;          // 0..7
    const int wm = wave >> 1;           // 0..3 (row group of 64)
    const int wn = wave & 1;            // 0..1 (col group of 64)
    const int lo = lane & 15, hi = lane >> 4;

    // bijective XCD swizzle (nblk = 272 = 8*34, r == 0)
    const int orig = blockIdx.x;
    const int q = nblk >> 3, r = nblk & 7;
    const int xcd = orig & 7, idx = orig >> 3;
    const int bid = (xcd < r ? xcd * (q + 1) : r * (q + 1) + (xcd - r) * q) + idx;

    // cover index: bid = I*(I+1) + J, J in [0, 2I+2)
    int bi = (int)((sqrtf(4.0f * (float)bid + 1.0f) - 1.0f) * 0.5f);
    while ((bi + 1) * (bi + 2) <= bid) ++bi;
    while (bi * (bi + 1) > bid) --bi;
    const int bj = bid - bi * (bi + 1);
    const int rowBase = bi * BM;
    const int colBase = bj * BN;

    // staging: A = 16 chunks of 1KB (16 rows x 32k), B = 8 chunks.
    // wave w stages A-chunks {w, w+8} and B-chunk {w}: 3 GLD16/step.
    const int lrow = lane >> 2;       // row within 16-row chunk
    const int lk   = (lane & 3) * 8;  // bf16 k-offset 0,8,16,24
    const unsigned short* gA0 = Xbf + (size_t)(rowBase + wave * 16 + lrow) * d + lk;
    const unsigned short* gA1 = gA0 + (size_t)128 * d;
    const unsigned short* gB0 = Xbf + (size_t)(colBase + wave * 16 + lrow) * d + lk;

#define STAGE(bufi, k0)                                                   \
    do {                                                                  \
        GLD16(gA0 + (k0), &ldsA[bufi][wave * 512]);                       \
        GLD16(gA1 + (k0), &ldsA[bufi][(8 + wave) * 512]);                 \
        GLD16(gB0 + (k0), &ldsB[bufi][wave * 512]);                       \
    } while (0)

    f32x4 acc[4][4] = {};

    const int nt = d / BK;
    int cur = 0;
    STAGE(0, 0);
    for (int t = 0; t < nt; ++t) {
        if (t + 1 < nt) {
            STAGE(cur ^ 1, (t + 1) * BK);
            asm volatile("s_waitcnt vmcnt(3)" ::: "memory");  // cur's data landed
        } else {
            asm volatile("s_waitcnt vmcnt(0)" ::: "memory");
        }
        asm volatile("s_barrier" ::: "memory");               // all waves' data in
        bf16x8 a[4], b[4];
#pragma unroll
        for (int mi = 0; mi < 4; ++mi)
            a[mi] = *(const bf16x8*)&ldsA[cur][(wm * 64 + mi * 16 + lo) * BK + hi * 8];
#pragma unroll
        for (int ni = 0; ni < 4; ++ni)
            b[ni] = *(const bf16x8*)&ldsB[cur][(wn * 64 + ni * 16 + lo) * BK + hi * 8];
#pragma unroll
        for (int mi = 0; mi < 4; ++mi)
#pragma unroll
            for (int ni = 0; ni < 4; ++ni)
                acc[mi][ni] = __builtin_amdgcn_mfma_f32_16x16x32_bf16(
                    a[mi], b[ni], acc[mi][ni], 0, 0, 0);
        asm volatile("s_barrier" ::: "memory");               // reads done; next stage may overwrite
        cur ^= 1;
    }

    // ---------------- epilogue (dual-side hard mining; verified shape) -----
    float sqj[4];
    int   tj[4];
#pragma unroll
    for (int ni = 0; ni < 4; ++ni) {
        const int gj = colBase + wn * 64 + ni * 16 + lo;
        sqj[ni] = sqg[gj];
        tj[ni]  = tgt[gj];
    }
    float cap[4], can[4];
#pragma unroll
    for (int ni = 0; ni < 4; ++ni) { cap[ni] = 0.0f; can[ni] = __uint_as_float(0x7F800000u); }

#pragma unroll
    for (int mi = 0; mi < 4; ++mi) {
#pragma unroll
        for (int j = 0; j < 4; ++j) {
            const int gi = rowBase + wm * 64 + mi * 16 + hi * 4 + j;
            const float sqi = sqg[gi];
            const int   ti  = tgt[gi];
            float ap = 0.0f;
            float an = __uint_as_float(0x7F800000u);
#pragma unroll
            for (int ni = 0; ni < 4; ++ni) {
                const float d2 = sqi + sqj[ni] - 2.0f * acc[mi][ni][j];
                const float dist = sqrtf(fmaxf(d2, EPS));
                if (ti == tj[ni]) {
                    ap = fmaxf(ap, dist);
                    cap[ni] = fmaxf(cap[ni], dist);
                } else {
                    an = fminf(an, dist);
                    can[ni] = fminf(can[ni], dist);
                }
            }
            // row-side: reduce across the 16 lanes (lo) holding this row
#pragma unroll
            for (int m = 1; m < 16; m <<= 1) {
                ap = fmaxf(ap, __shfl_xor(ap, m, 64));
                an = fminf(an, __shfl_xor(an, m, 64));
            }
            if (lo == 0) {
                atomicMax(&apb[gi], __float_as_uint(ap));
                atomicMin(&anb[gi], __float_as_uint(an));
            }
        }
    }
    // col-side: reduce across the 4 hi groups (lane bits 4,5); always done
    // (cover tiles are not a partition; idempotent updates make this safe)
#pragma unroll
    for (int ni = 0; ni < 4; ++ni) {
        float ap = cap[ni], an = can[ni];
#pragma unroll
        for (int m = 16; m < 64; m <<= 1) {
            ap = fmaxf(ap, __shfl_xor(ap, m, 64));
            an = fminf(an, __shfl_xor(an, m, 64));
        }
        if (hi == 0) {
            const int gj = colBase + wn * 64 + ni * 16 + lo;
            atomicMax(&apb[gj], __float_as_uint(ap));
            atomicMin(&anb[gj], __float_as_uint(an));
        }
    }

    // ---------------- last-block finalize ----------------
    __threadfence();
    __syncthreads();
    __shared__ int lastFlag;
    if (tid == 0) {
        unsigned prev = __hip_atomic_fetch_add(ctr, 1u, __ATOMIC_ACQ_REL,
                                               __HIP_MEMORY_SCOPE_AGENT);
        lastFlag = (prev == (unsigned)(nblk - 1)) ? 1 : 0;
    }
    __syncthreads();
    if (lastFlag) {
        float ls = 0.0f, pc = 0.0f;
        for (int i = tid; i < n; i += 512) {
            const float ap = __uint_as_float(__hip_atomic_load(
                &apb[i], __ATOMIC_RELAXED, __HIP_MEMORY_SCOPE_AGENT));
            const float an = __uint_as_float(__hip_atomic_load(
                &anb[i], __ATOMIC_RELAXED, __HIP_MEMORY_SCOPE_AGENT));
            ls += fmaxf(MARGIN - (an - ap), 0.0f);
            pc += (an > ap) ? 1.0f : 0.0f;
        }
        __shared__ float rl[8], rp[8];
        for (int off = 32; off > 0; off >>= 1) {
            ls += __shfl_down(ls, off, 64);
            pc += __shfl_down(pc, off, 64);
        }
        if ((tid & 63) == 0) { rl[tid >> 6] = ls; rp[tid >> 6] = pc; }
        __syncthreads();
        if (tid == 0) {
            float L = 0.0f, P = 0.0f;
#pragma unroll
            for (int w = 0; w < 8; ++w) { L += rl[w]; P += rp[w]; }
            out[0] = L / (float)n;
            out[1] = P / (float)n;
        }
    }
}

// ---------------------------------------------------------------------------
// Fallback path (only if ws_size too small): pure fp32, zero workspace.
// ---------------------------------------------------------------------------
__global__ __launch_bounds__(256) void fb_zero(float* __restrict__ out) {
    if (threadIdx.x == 0) { out[0] = 0.0f; out[1] = 0.0f; }
}

__global__ __launch_bounds__(256) void fb_row(
    const float* __restrict__ X, const int* __restrict__ tgt,
    float* __restrict__ out, int n, int d) {
    __shared__ float xi[4096];  // supports d <= 4096
    const int i = blockIdx.x;
    const int tid = threadIdx.x;
    for (int k = tid; k < d; k += 256) xi[k] = X[(size_t)i * d + k];
    __syncthreads();
    const int ti = tgt[i];
    float ap = 0.0f;
    float an = __uint_as_float(0x7F800000u);
    for (int j = tid; j < n; j += 256) {
        const float4* Xj = (const float4*)(X + (size_t)j * d);
        float s = 0.0f;
        for (int k4 = 0; k4 < (d >> 2); ++k4) {
            float4 v = Xj[k4];
            float4 u = *(const float4*)&xi[k4 * 4];
            float dx = u.x - v.x, dy = u.y - v.y, dz = u.z - v.z, dw = u.w - v.w;
            s += dx * dx + dy * dy + dz * dz + dw * dw;
        }
        const float dist = sqrtf(fmaxf(s, EPS));
        if (tgt[j] == ti) ap = fmaxf(ap, dist);
        else              an = fminf(an, dist);
    }
    for (int m = 1; m < 64; m <<= 1) {
        ap = fmaxf(ap, __shfl_xor(ap, m, 64));
        an = fminf(an, __shfl_xor(an, m, 64));
    }
    __shared__ float rap[4], ran[4];
    const int wave = tid >> 6, lane = tid & 63;
    if (lane == 0) { rap[wave] = ap; ran[wave] = an; }
    __syncthreads();
    if (tid == 0) {
        ap = fmaxf(fmaxf(rap[0], rap[1]), fmaxf(rap[2], rap[3]));
        an = fminf(fminf(ran[0], ran[1]), fminf(ran[2], ran[3]));
        atomicAdd(&out[0], fmaxf(MARGIN - (an - ap), 0.0f));
        atomicAdd(&out[1], (an > ap) ? 1.0f : 0.0f);
    }
}

__global__ __launch_bounds__(64) void fb_scale(float* __restrict__ out, float inv_n) {
    if (threadIdx.x == 0) { out[0] *= inv_n; out[1] *= inv_n; }
}

// ---------------------------------------------------------------------------
extern "C" void kernel_launch(void* const* d_in, const int* in_sizes, int n_in,
                              void* d_out, int out_size, void* d_ws, size_t ws_size,
                              hipStream_t stream) {
    const float* X   = (const float*)d_in[0];
    const int*   tgt = (const int*)d_in[1];
    const int n = in_sizes[1];
    const int d = in_sizes[0] / n;

    const size_t need = (size_t)n * d * 2 + (size_t)n * 4 * 3 + 4;
    if (ws_size >= need && (n % BM) == 0 && (d % (2 * BK)) == 0) {
        char* ws = (char*)d_ws;
        unsigned short* Xbf = (unsigned short*)ws;                 // n*d*2 B
        float*    sqg = (float*)(ws + (size_t)n * d * 2);          // n*4 B
        unsigned* apb = (unsigned*)((char*)sqg + (size_t)n * 4);   // n*4 B
        unsigned* anb = apb + n;                                   // n*4 B
        unsigned* ctr = anb + n;                                   // 4 B

        const int nbI = n / BM;                 // 16
        const int nblk = nbI * (nbI + 1);       // 272
        prep_kernel<<<n / 4, 256, 0, stream>>>(X, Xbf, sqg, apb, anb, ctr, d);
        tri_gemm<<<nblk, 512, 0, stream>>>(Xbf, sqg, tgt, apb, anb, ctr,
                                           (float*)d_out, n, d, nblk);
    } else {
        fb_zero<<<1, 256, 0, stream>>>((float*)d_out);
        fb_row<<<n, 256, 0, stream>>>(X, tgt, (float*)d_out, n, d);
        fb_scale<<<1, 64, 0, stream>>>((float*)d_out, 1.0f / (float)n);
    }
}